// Round 1
// baseline (218.672 us; speedup 1.0000x reference)
//
#include <hip/hip_runtime.h>

#define BATCH 4
#define CIN 1024      // channels per input tensor
#define T 512
#define HW 49
#define C 2048        // concat channels
#define D 128         // SIM_DIM
#define L 101         // LOOKUP
#define HALF 50
#define OUTD 128

// ---------------------------------------------------------------------------
// Kernel 1: spatial mean over 7x7=49 for both inputs -> feats[b][c][t] fp32
// Rows are contiguous 49-float slabs. Cooperative LDS staging gives aligned,
// fully-coalesced float4 loads (row base = 196B is NOT 16B aligned).
// ---------------------------------------------------------------------------
__global__ __launch_bounds__(256) void mean_kernel(const float* __restrict__ x1,
                                                   const float* __restrict__ x2,
                                                   float* __restrict__ feats) {
    __shared__ __align__(16) float lds[64 * HW];  // 3136 floats = 12.25 KB
    const long long Mrows = (long long)BATCH * CIN * T;  // 2097152 per input
    long long row0 = (long long)blockIdx.x * 64;
    const float* src;
    long long m0;
    int half;
    if (row0 < Mrows) { src = x1; m0 = row0; half = 0; }
    else              { src = x2; m0 = row0 - Mrows; half = 1; }

    const float4* src4 = reinterpret_cast<const float4*>(src + m0 * HW);
    float4* lds4 = reinterpret_cast<float4*>(lds);
    int tid = threadIdx.x;
    // 64 rows * 49 = 3136 floats = 784 float4
#pragma unroll
    for (int i = 0; i < 3; ++i) lds4[tid + i * 256] = src4[tid + i * 256];
    if (tid < 16) lds4[768 + tid] = src4[768 + tid];
    __syncthreads();

    int r = tid >> 2, p = tid & 3;  // 4 threads per row
    float s = 0.f;
#pragma unroll
    for (int k = 0; k < 13; ++k) {
        int j = p * 13 + k;
        if (j < HW) s += lds[r * HW + j];
    }
    s += __shfl_xor(s, 1);
    s += __shfl_xor(s, 2);
    if (p == 0) {
        long long m = m0 + r;
        long long b = m >> 19;                 // / (1024*512)
        long long rem = m & ((1LL << 19) - 1); // c*512 + t
        long long oidx = (b << 20) + ((long long)half << 19) + rem;
        feats[oidx] = s * (1.0f / 49.0f);
    }
}

// ---------------------------------------------------------------------------
// Kernel 2: transpose Wp [D][C] -> WpT [C][D], Wf [OUTD][L] -> WfT [L][OUTD]
// ---------------------------------------------------------------------------
__global__ __launch_bounds__(256) void prep_kernel(const float* __restrict__ Wp,
                                                   const float* __restrict__ Wf,
                                                   float* __restrict__ WpT,
                                                   float* __restrict__ WfT) {
    int tid = blockIdx.x * 256 + threadIdx.x;
    if (tid < C * D) {
        int c = tid >> 7, d = tid & 127;
        WpT[tid] = Wp[d * C + c];
    }
    if (tid < L * OUTD) {
        int l = tid >> 7, o = tid & 127;
        WfT[tid] = Wf[o * L + l];
    }
}

// ---------------------------------------------------------------------------
// Kernel 3: projection, split-K. x[b,t,d] = sum_c feats[b,c,t] * WpT[c,d]
// grid = 4(b) * 16(t-tile of 32) * 8(k-chunk of 256) = 512 blocks, 256 thr.
// Each thread: 4t x 4d register tile. Partials -> part[kc][b*T+t][d].
// ---------------------------------------------------------------------------
__global__ __launch_bounds__(256) void proj_kernel(const float* __restrict__ feats,
                                                   const float* __restrict__ WpT,
                                                   float* __restrict__ part) {
    int blk = blockIdx.x;
    int kc = blk & 7;
    int tt = (blk >> 3) & 15;
    int b  = blk >> 7;
    int c0 = kc * 256;
    int t0 = tt * 32;

    __shared__ __align__(16) float fl[256 * 32];  // feats[c0..c0+256)[t0..t0+32) 32KB
    const float4* feats4 = reinterpret_cast<const float4*>(feats);
    float4* fl4 = reinterpret_cast<float4*>(fl);
    int tid = threadIdx.x;
#pragma unroll
    for (int i = 0; i < 8; ++i) {
        int idx = i * 256 + tid;        // 2048 float4 total
        int c = idx >> 3, tq = idx & 7;
        fl4[idx] = feats4[((long long)(b * C + c0 + c) << 7) + (t0 >> 2) + tq];
    }
    __syncthreads();

    int dg = tid & 31;   // d = dg*4 .. dg*4+3
    int tg = tid >> 5;   // t = t0 + tg*4 .. +3
    float acc[4][4] = {};
    const float4* WpT4 = reinterpret_cast<const float4*>(WpT);
#pragma unroll 4
    for (int c = 0; c < 256; ++c) {
        float4 fv = *reinterpret_cast<const float4*>(&fl[c * 32 + tg * 4]);
        float4 wv = WpT4[(c0 + c) * 32 + dg];
        float fvv[4] = {fv.x, fv.y, fv.z, fv.w};
        float wvv[4] = {wv.x, wv.y, wv.z, wv.w};
#pragma unroll
        for (int i = 0; i < 4; ++i)
#pragma unroll
            for (int j = 0; j < 4; ++j)
                acc[i][j] += fvv[i] * wvv[j];
    }

    float4* part4 = reinterpret_cast<float4*>(part);
#pragma unroll
    for (int i = 0; i < 4; ++i) {
        float4 st = make_float4(acc[i][0], acc[i][1], acc[i][2], acc[i][3]);
        part4[(((long long)kc * (BATCH * T) + b * T + (t0 + tg * 4 + i)) << 5) + dg] = st;
    }
}

// ---------------------------------------------------------------------------
// Kernel 4: reduce split-K partials + L2 normalize -> xn[b*T+t][d]
// ---------------------------------------------------------------------------
__global__ __launch_bounds__(128) void norm_kernel(const float* __restrict__ part,
                                                   float* __restrict__ xn) {
    int bt = blockIdx.x;
    int tid = threadIdx.x;
    float v = 0.f;
#pragma unroll
    for (int kc = 0; kc < 8; ++kc)
        v += part[(long long)kc * (BATCH * T * D) + bt * D + tid];
    float sq = v * v;
#pragma unroll
    for (int off = 1; off < 64; off <<= 1) sq += __shfl_xor(sq, off);
    __shared__ float red[2];
    if ((tid & 63) == 0) red[tid >> 6] = sq;
    __syncthreads();
    float n2 = red[0] + red[1];
    float scale = 1.0f / fmaxf(sqrtf(n2), 1e-12f);
    xn[bt * D + tid] = v * scale;
}

// ---------------------------------------------------------------------------
// Kernel 5: banded sims + FC + bias + relu.
// Block per (b,t), 128 threads. Thread l<101: sim[l] = <x_t, x_{t+l-50}> (0
// outside band = zero pad). Then thread o: out = relu(bf[o] + sum_l sim*WfT).
// ---------------------------------------------------------------------------
__global__ __launch_bounds__(128) void simfc_kernel(const float* __restrict__ xn,
                                                    const float* __restrict__ WfT,
                                                    const float* __restrict__ bf,
                                                    float* __restrict__ out) {
    int bt = blockIdx.x;
    int b = bt >> 9, t = bt & 511;
    int tid = threadIdx.x;
    __shared__ __align__(16) float q[D];
    __shared__ float sim[L];
    q[tid] = xn[bt * D + tid];
    __syncthreads();

    if (tid < L) {
        float acc = 0.f;
        int s = t + tid - HALF;
        if (s >= 0 && s < T) {
            const float4* xr = reinterpret_cast<const float4*>(xn + (((long long)b << 9) + s) * D);
            const float4* q4 = reinterpret_cast<const float4*>(q);
#pragma unroll
            for (int d4 = 0; d4 < D / 4; ++d4) {
                float4 xv = xr[d4];
                float4 qv = q4[d4];
                acc += qv.x * xv.x + qv.y * xv.y + qv.z * xv.z + qv.w * xv.w;
            }
        }
        sim[tid] = acc;
    }
    __syncthreads();

    float acc = bf[tid];
#pragma unroll 4
    for (int l = 0; l < L; ++l) acc += sim[l] * WfT[l * OUTD + tid];
    out[bt * OUTD + tid] = fmaxf(acc, 0.0f);
}

// ---------------------------------------------------------------------------
extern "C" void kernel_launch(void* const* d_in, const int* in_sizes, int n_in,
                              void* d_out, int out_size, void* d_ws, size_t ws_size,
                              hipStream_t stream) {
    const float* x1 = (const float*)d_in[0];
    const float* x2 = (const float*)d_in[1];
    const float* Wp = (const float*)d_in[2];
    const float* Wf = (const float*)d_in[3];
    const float* bf = (const float*)d_in[4];
    float* out = (float*)d_out;

    float* ws = (float*)d_ws;
    float* feats = ws;                        // 4*2048*512     = 4194304 floats
    float* WpT   = feats + 4194304;           // 2048*128       = 262144
    float* WfT   = WpT + 262144;              // 101*128        = 12928
    float* part  = WfT + 12928;               // 8*4*512*128    = 2097152
    float* xn    = part + 2097152;            // 4*512*128      = 262144
    // total ~6.83M floats = 27.3 MB

    hipLaunchKernelGGL(prep_kernel, dim3(1024), dim3(256), 0, stream, Wp, Wf, WpT, WfT);
    hipLaunchKernelGGL(mean_kernel, dim3(65536), dim3(256), 0, stream, x1, x2, feats);
    hipLaunchKernelGGL(proj_kernel, dim3(512), dim3(256), 0, stream, feats, WpT, part);
    hipLaunchKernelGGL(norm_kernel, dim3(2048), dim3(128), 0, stream, part, xn);
    hipLaunchKernelGGL(simfc_kernel, dim3(2048), dim3(128), 0, stream, xn, WfT, bf, out);
}